// Round 6
// baseline (466.434 us; speedup 1.0000x reference)
//
#include <hip/hip_runtime.h>
#include <cstdint>
#include <cmath>

// ---------------------------------------------------------------------------
// RegionSelection on MI355X (gfx950) — R7: K1 single-barrier F-double-buffer.
//
//   P0: split W1, W2 into u16 hi/lo planes ([n][k])
//   K1: h1 = relu(W1 @ feat + b1). NEW: F double-buffered -> ONE barrier
//       per k-iter. Order: barrier -> issue next F-loads + W-DMA ->
//       MFMA(cur) -> STAGE_F(cur^1). F ds_writes overlap MFMA; global
//       loads span the MFMA phase. Epilogue: b64 LDS writes (i1 == i0+1).
//   K2: h2 = relu(W2 @ h1 + b2). R6's all-DMA kernel (unchanged).
//   K3/K4/K5 unchanged.
//
// Numerics bit-identical to R1..R6: absmax must stay exactly 0.001953125.
//
// d_out scratch (float units):
//   h1hi [0, 8388608)         h1lo [8388608, 16777216)    K1 -> K2
//   h2   [16777216, 25165824)                             K2 -> K3
//   w1hi [25165824, 25427968) w1lo [25427968, 25690112)   P0 -> K1
//   w2hi [25690112, 25755648) w2lo [25755648, 25821184)   P0 -> K2
// max 25821184 < 42467328 (regions area, written last by K5).
// ---------------------------------------------------------------------------

typedef float f4 __attribute__((ext_vector_type(4)));
typedef _Float16 f16x8 __attribute__((ext_vector_type(8)));
typedef int i4 __attribute__((ext_vector_type(4)));
typedef int i2 __attribute__((ext_vector_type(2)));
typedef unsigned short u16x4 __attribute__((ext_vector_type(4)));

#define M_PIX 32768
#define COORDS_OFF 42467328
#define ATT_OFF 42467712

#define H1HI_OFF 0
#define H1LO_OFF 8388608
#define H2_OFF 16777216
#define W1HI_OFF 25165824
#define W1LO_OFF 25427968
#define W2HI_OFF 25690112
#define W2LO_OFF 25755648

#define GLOAD16(gp, lp) \
    __builtin_amdgcn_global_load_lds( \
        (const __attribute__((address_space(1))) unsigned int*)(gp), \
        (__attribute__((address_space(3))) unsigned int*)(lp), 16, 0, 0)

// swizzled int-index within an 8KB tile (128 rows x 16 ints = 32 f16/row).
// idx = (row*16 + k16/2) ^ ((row&7)<<2). Bijective; HW-verified (R3 W-DMA).
// Inverse: row = (L>>4) ^ (((L>>4)>>2)&1); kint = (L&15) ^ ((row&3)<<2).
__device__ __forceinline__ int swz(int row, int k16) {
    return ((row << 4) + (k16 >> 1)) ^ ((row & 7) << 2);
}

__device__ __forceinline__ int split_pack(float v0, float v1, int& lop) {
    _Float16 h0 = (_Float16)v0, h1 = (_Float16)v1;
    float r0 = v0 - (float)h0, r1 = v1 - (float)h1;
    _Float16 l0 = (_Float16)r0, l1 = (_Float16)r1;
    unsigned int uh0 = __builtin_bit_cast(unsigned short, h0);
    unsigned int uh1 = __builtin_bit_cast(unsigned short, h1);
    unsigned int ul0 = __builtin_bit_cast(unsigned short, l0);
    unsigned int ul1 = __builtin_bit_cast(unsigned short, l1);
    lop = (int)(ul0 | (ul1 << 16));
    return (int)(uh0 | (uh1 << 16));
}

// ---------------------------------------------------------------------------
// P0: split a fp32 array into u16 hi/lo planes ([n][k] layout). n4 = count/4.
// ---------------------------------------------------------------------------
__global__ __launch_bounds__(256) void split_plane(
    const float* __restrict__ src, unsigned short* __restrict__ hi,
    unsigned short* __restrict__ lo, int n4)
{
    const int i = blockIdx.x * 256 + threadIdx.x;
    if (i >= n4) return;
    f4 v = *(const f4*)(src + 4 * (size_t)i);
    u16x4 hv, lv;
    #pragma unroll
    for (int j = 0; j < 4; ++j) {
        _Float16 h = (_Float16)v[j];
        _Float16 l = (_Float16)(v[j] - (float)h);
        hv[j] = __builtin_bit_cast(unsigned short, h);
        lv[j] = __builtin_bit_cast(unsigned short, l);
    }
    *(u16x4*)(hi + 4 * (size_t)i) = hv;
    *(u16x4*)(lo + 4 * (size_t)i) = lv;
}

// ---------------------------------------------------------------------------
// K1: h1 = relu(W1 @ feat + b1). Block 128n x 128px, 4 waves, K_STEP 32.
// W via global_load_lds (dbuf); F split on the fly, DOUBLE-BUFFERED.
// One barrier per k-iter. Epilogue -> tiled split images (b64 writes).
// Grid: 1024 = 4 nb x 256 pb, XCD-grouped.
// LDS (ints): W buf0 [0,4096) (hi 0, lo 2048), W buf1 [4096,8192);
//             F buf0 [8192,12288) (hi, lo),    F buf1 [12288,16384).
// ---------------------------------------------------------------------------
__global__ __launch_bounds__(256, 2) void gemm_k1(
    const unsigned short* __restrict__ WH, const unsigned short* __restrict__ WL,
    const float* __restrict__ feat, const float* __restrict__ bias,
    unsigned int* __restrict__ OHI, unsigned int* __restrict__ OLO)
{
    constexpr int Kdim = 1024;
    __shared__ int lds[16384];    // 64 KB

    const int t = threadIdx.x;
    const int lane = t & 63;
    const int wave = t >> 6;
    const int wn = wave >> 1, wp = wave & 1;

    const int f  = blockIdx.x;
    const int nb = (f >> 3) & 3;
    const int pb = (f & 7) | ((f >> 5) << 3);
    const int n0  = nb * 128;
    const int px0 = pb * 128;

    const int rl = t & 127;          // F row (px) this thread stages
    const int kb = (t >> 7) * 16;    // k-half

    const float* F32 = feat + ((size_t)(px0 >> 10) << 20) + (px0 & 1023) + rl;

    // W DMA source pre-swizzle (R3-verified)
    int wg_off[2];
    #pragma unroll
    for (int j = 0; j < 2; ++j) {
        const int i  = 2 * wave + j;
        const int rL = 16 * i + (lane >> 2);
        const int r  = rL ^ ((rL >> 2) & 1);
        const int c  = (4 * (lane & 3)) ^ ((r & 3) << 2);
        wg_off[j] = (n0 + r) * Kdim + 2 * c;
    }

    f4 acc[4][4];
    #pragma unroll
    for (int i = 0; i < 4; ++i)
        #pragma unroll
        for (int j = 0; j < 4; ++j) acc[i][j] = (f4){0.f, 0.f, 0.f, 0.f};

    float fv[16];

    auto LOADS_F = [&](int k0) {
        #pragma unroll
        for (int j = 0; j < 16; ++j)
            fv[j] = F32[(size_t)(k0 + kb + j) * 1024];
    };
    auto W_GLOADS = [&](int buf, int k0) {
        const int wb = buf * 4096;
        #pragma unroll
        for (int j = 0; j < 2; ++j) {
            const int i = 2 * wave + j;
            GLOAD16(WH + wg_off[j] + k0, &lds[wb + 256 * i]);
            GLOAD16(WL + wg_off[j] + k0, &lds[wb + 2048 + 256 * i]);
        }
    };
    auto STAGE_F = [&](int buf) {
        const int fb = 8192 + buf * 4096;
        #pragma unroll
        for (int g = 0; g < 2; ++g) {
            i4 hp, lp;
            #pragma unroll
            for (int j = 0; j < 4; ++j) {
                int lo;
                hp[j] = split_pack(fv[8 * g + 2 * j], fv[8 * g + 2 * j + 1], lo);
                lp[j] = lo;
            }
            *(i4*)&lds[fb        + swz(rl, kb + 8 * g)] = hp;
            *(i4*)&lds[fb + 2048 + swz(rl, kb + 8 * g)] = lp;
        }
    };

    const int rA0 = 64 * wn + (lane & 15);
    const int rB0 = 64 * wp + (lane & 15);
    const int kg  = (lane >> 4) * 8;

    // prologue: fill buf0 (F stage + W DMA)
    LOADS_F(0);
    W_GLOADS(0, 0);
    STAGE_F(0);
    int cur = 0;
    for (int k0 = 0; k0 < Kdim; k0 += 32) {
        __syncthreads();   // drains W DMA(cur) [vmcnt] + F writes(cur) [lgkm];
                           // also fences prev iter's reads of cur before overwrite
        const bool nxt = (k0 + 32 < Kdim);
        if (nxt) { LOADS_F(k0 + 32); W_GLOADS(cur ^ 1, k0 + 32); }

        const int wb = cur * 4096, fb = 8192 + cur * 4096;
        f16x8 bh[4], bl[4];
        #pragma unroll
        for (int nf = 0; nf < 4; ++nf) {
            bh[nf] = *(const f16x8*)&lds[fb        + swz(rB0 + 16 * nf, kg)];
            bl[nf] = *(const f16x8*)&lds[fb + 2048 + swz(rB0 + 16 * nf, kg)];
        }
        #pragma unroll
        for (int m = 0; m < 4; ++m) {
            f16x8 ah = *(const f16x8*)&lds[wb        + swz(rA0 + 16 * m, kg)];
            f16x8 al = *(const f16x8*)&lds[wb + 2048 + swz(rA0 + 16 * m, kg)];
            #pragma unroll
            for (int nf = 0; nf < 4; ++nf) {
                acc[m][nf] = __builtin_amdgcn_mfma_f32_16x16x32_f16(ah, bh[nf], acc[m][nf], 0, 0, 0);
                acc[m][nf] = __builtin_amdgcn_mfma_f32_16x16x32_f16(ah, bl[nf], acc[m][nf], 0, 0, 0);
                acc[m][nf] = __builtin_amdgcn_mfma_f32_16x16x32_f16(al, bh[nf], acc[m][nf], 0, 0, 0);
            }
        }
        if (nxt) STAGE_F(cur ^ 1);   // writes to OTHER buffer: overlaps MFMA,
                                     // no barrier needed before next iter's top
        cur ^= 1;
    }

    // epilogue: h1 -> tiled split images via LDS bounce (b64 writes).
    // C/D layout: col(px) = lane&15, row(n) = (lane>>4)*4 + reg.
    __syncthreads();   // last iter's LDS reads done before full-LDS reuse
    #pragma unroll
    for (int m = 0; m < 4; ++m) {
        const int n_l = 64 * wn + 4 * (lane >> 4) + 16 * m;   // local n
        const f4 bv = *(const f4*)&bias[n0 + n_l];
        const int kb_l = n_l >> 5;
        #pragma unroll
        for (int nf = 0; nf < 4; ++nf) {
            const int row = 64 * wp + (lane & 15) + 16 * nf;  // local px
            float v0 = fmaxf(acc[m][nf][0] + bv[0], 0.0f);
            float v1 = fmaxf(acc[m][nf][1] + bv[1], 0.0f);
            float v2 = fmaxf(acc[m][nf][2] + bv[2], 0.0f);
            float v3 = fmaxf(acc[m][nf][3] + bv[3], 0.0f);
            int lo0, lo1;
            int hi0 = split_pack(v0, v1, lo0);
            int hi1 = split_pack(v2, v3, lo1);
            // i1 == i0+1 (c/2 even, XOR field is bits 2..4 -> +1 can't cross)
            const int i0 = swz(row, (n_l & 31));
            *(i2*)&lds[kb_l * 2048 + i0]        = (i2){hi0, hi1};
            *(i2*)&lds[8192 + kb_l * 2048 + i0] = (i2){lo0, lo1};
        }
    }
    __syncthreads();
    // coalesced write-out: 8 groups (4 tiles x 2 planes) x 32 threads
    const int g = t >> 5;
    const int l32 = t & 31;
    unsigned int* dst = ((g >> 2) ? OLO : OHI)
                      + (((size_t)pb * 16 + 4 * nb + (g & 3)) << 11);
    const int* src = &lds[(g >> 2) * 8192 + (g & 3) * 2048];
    #pragma unroll
    for (int q = 0; q < 16; ++q)
        *(i4*)(dst + 128 * q + 4 * l32) = *(const i4*)(src + 128 * q + 4 * l32);
}

// ---------------------------------------------------------------------------
// K2: h2 = relu(W2 @ h1 + b2). All-DMA kernel (R5/R6-verified). NKB=16.
// Grid: 512 = 2 nb x 256 pb, XCD-grouped. f32 out.
// ---------------------------------------------------------------------------
__global__ __launch_bounds__(256, 2) void gemm_k2(
    const unsigned short* __restrict__ WH, const unsigned short* __restrict__ WL,
    const unsigned int* __restrict__ FH, const unsigned int* __restrict__ FL,
    const float* __restrict__ bias, float* __restrict__ OUT)
{
    constexpr int NKB = 16;
    constexpr int Kdim = NKB * 32;
    __shared__ int lds[16384];   // W dbuf [0,8192), F dbuf [8192,16384)

    const int t = threadIdx.x;
    const int lane = t & 63;
    const int wave = t >> 6;
    const int wn = wave >> 1, wp = wave & 1;

    const int f   = blockIdx.x;
    const int nb  = (f >> 3) & 1;
    const int lpb = (f & 7) | ((f >> 4) << 3);
    const int n0  = nb * 128;
    const int px0 = lpb * 128;

    int wg_off[2];
    #pragma unroll
    for (int j = 0; j < 2; ++j) {
        const int i  = 2 * wave + j;
        const int rL = 16 * i + (lane >> 2);
        const int r  = rL ^ ((rL >> 2) & 1);
        const int c  = (4 * (lane & 3)) ^ ((r & 3) << 2);
        wg_off[j] = (n0 + r) * Kdim + 2 * c;
    }

    const unsigned int* fhb = FH + ((size_t)lpb * NKB << 11) + 256 * (2 * wave) + 4 * lane;
    const unsigned int* flb = FL + ((size_t)lpb * NKB << 11) + 256 * (2 * wave) + 4 * lane;

    f4 acc[4][4];
    #pragma unroll
    for (int i = 0; i < 4; ++i)
        #pragma unroll
        for (int j = 0; j < 4; ++j) acc[i][j] = (f4){0.f, 0.f, 0.f, 0.f};

    auto DMA = [&](int buf, int kbi) {
        const int wb = buf * 4096, fb = 8192 + buf * 4096;
        const int k0 = kbi * 32;
        #pragma unroll
        for (int j = 0; j < 2; ++j) {
            const int i = 2 * wave + j;
            GLOAD16(WH + wg_off[j] + k0, &lds[wb + 256 * i]);
            GLOAD16(WL + wg_off[j] + k0, &lds[wb + 2048 + 256 * i]);
            GLOAD16(fhb + ((size_t)kbi << 11) + 256 * j, &lds[fb + 256 * i]);
            GLOAD16(flb + ((size_t)kbi << 11) + 256 * j, &lds[fb + 2048 + 256 * i]);
        }
    };

    const int rA0 = 64 * wn + (lane & 15);
    const int rB0 = 64 * wp + (lane & 15);
    const int kg  = (lane >> 4) * 8;

    DMA(0, 0);
    int cur = 0;
    for (int kbi = 0; kbi < NKB; ++kbi) {
        __syncthreads();   // drains DMA(cur); fences prev reads of cur^1
        if (kbi + 1 < NKB) DMA(cur ^ 1, kbi + 1);

        const int wb = cur * 4096, fb = 8192 + cur * 4096;
        f16x8 bh[4], bl[4];
        #pragma unroll
        for (int nf = 0; nf < 4; ++nf) {
            bh[nf] = *(const f16x8*)&lds[fb + swz(rB0 + 16 * nf, kg)];
            bl[nf] = *(const f16x8*)&lds[fb + 2048 + swz(rB0 + 16 * nf, kg)];
        }
        #pragma unroll
        for (int m = 0; m < 4; ++m) {
            f16x8 ah = *(const f16x8*)&lds[wb + swz(rA0 + 16 * m, kg)];
            f16x8 al = *(const f16x8*)&lds[wb + 2048 + swz(rA0 + 16 * m, kg)];
            #pragma unroll
            for (int nf = 0; nf < 4; ++nf) {
                acc[m][nf] = __builtin_amdgcn_mfma_f32_16x16x32_f16(ah, bh[nf], acc[m][nf], 0, 0, 0);
                acc[m][nf] = __builtin_amdgcn_mfma_f32_16x16x32_f16(ah, bl[nf], acc[m][nf], 0, 0, 0);
                acc[m][nf] = __builtin_amdgcn_mfma_f32_16x16x32_f16(al, bh[nf], acc[m][nf], 0, 0, 0);
            }
        }
        cur ^= 1;
    }

    const int pxE = px0 + 64 * wp + (lane & 15);
    const int nE  = n0 + 64 * wn + 4 * (lane >> 4);
    #pragma unroll
    for (int m = 0; m < 4; ++m) {
        const int n_m = nE + 16 * m;
        const f4 bv = *(const f4*)&bias[n_m];
        #pragma unroll
        for (int nf = 0; nf < 4; ++nf) {
            const int p = pxE + 16 * nf;
            #pragma unroll
            for (int r = 0; r < 4; ++r)
                OUT[(size_t)(n_m + r) * M_PIX + p] = fmaxf(acc[m][nf][r] + bv[r], 0.0f);
        }
    }
}

// ---------------------------------------------------------------------------
// K3: att[p] = (sigmoid(b3 + sum_k w3[k]*h2[k][p]) + cam[p]) * 0.5
// ---------------------------------------------------------------------------
__global__ __launch_bounds__(256) void layer3_att(
    const float* __restrict__ h2, const float* __restrict__ w3,
    const float* __restrict__ b3, const float* __restrict__ cam,
    float* __restrict__ att)
{
    const int p = blockIdx.x * 256 + threadIdx.x;
    float s = b3[0];
    #pragma unroll 8
    for (int k = 0; k < 256; ++k)
        s = fmaf(w3[k], h2[(size_t)k * M_PIX + p], s);
    const float sg = 1.0f / (1.0f + expf(-s));
    att[p] = (sg + cam[p]) * 0.5f;
}

// ---------------------------------------------------------------------------
// K4: per-batch 3x (argmax + suppression). 1 wave per batch.
// ---------------------------------------------------------------------------
__global__ __launch_bounds__(64) void peaks_kernel(
    const float* __restrict__ att, float* __restrict__ coords,
    int* __restrict__ wsyx)
{
    const int b = blockIdx.x;
    const int lane = threadIdx.x;
    __shared__ float s[1024];
    for (int i = lane; i < 1024; i += 64) s[i] = att[b * 1024 + i];
    __syncthreads();

    for (int kpk = 0; kpk < 3; ++kpk) {
        float bv = -1.0f;
        int bi = 0x7fffffff;
        for (int i = lane; i < 1024; i += 64) {
            float v = s[i];
            if (v > bv) { bv = v; bi = i; }
        }
        for (int off = 32; off >= 1; off >>= 1) {
            float ov = __shfl_down(bv, off);
            int   oi = __shfl_down(bi, off);
            if (ov > bv || (ov == bv && oi < bi)) { bv = ov; bi = oi; }
        }
        bv = __shfl(bv, 0);
        bi = __shfl(bi, 0);

        int fy, fx;
        if (bv > 0.0f) { fy = bi >> 5; fx = bi & 31; }
        else           { fy = 16;      fx = 16; }

        for (int i = lane; i < 1024; i += 64) {
            const int y = i >> 5, x = i & 31;
            const int dy = y > fy ? y - fy : fy - y;
            const int dx = x > fx ? x - fx : fx - x;
            if (dy <= 5 && dx <= 5) s[i] = 0.0f;
        }
        __syncthreads();

        if (lane == 0) {
            int y1 = fy * 16 - 192; y1 = y1 < 0 ? 0 : (y1 > 128 ? 128 : y1);
            int x1 = fx * 16 - 192; x1 = x1 < 0 ? 0 : (x1 > 128 ? 128 : x1);
            const int idx = b * 3 + kpk;
            coords[idx * 4 + 0] = (float)x1;
            coords[idx * 4 + 1] = (float)y1;
            coords[idx * 4 + 2] = (float)(x1 + 384);
            coords[idx * 4 + 3] = (float)(y1 + 384);
            wsyx[idx * 2 + 0] = y1;
            wsyx[idx * 2 + 1] = x1;
        }
        __syncthreads();
    }
}

// ---------------------------------------------------------------------------
// K5: crop 96 regions x 3ch x 384x384 (x1 is 16-float aligned).
// ---------------------------------------------------------------------------
__global__ __launch_bounds__(256) void crop_kernel(
    const float* __restrict__ orig, const int* __restrict__ wsyx,
    float* __restrict__ out)
{
    const int id = blockIdx.x * 256 + threadIdx.x;
    const int r    = id / (3 * 384 * 96);
    const int rem  = id - r * (3 * 384 * 96);
    const int c    = rem / (384 * 96);
    const int rem2 = rem - c * (384 * 96);
    const int row  = rem2 / 96;
    const int col  = (rem2 - row * 96) * 4;
    const int b = r / 3;
    const int y1 = wsyx[r * 2], x1 = wsyx[r * 2 + 1];
    const float* src = orig + (size_t)b * 786432 + (size_t)c * 262144
                     + (size_t)(y1 + row) * 512 + x1 + col;
    *(f4*)(out + (size_t)id * 4) = *(const f4*)src;
}

// ---------------------------------------------------------------------------
extern "C" void kernel_launch(void* const* d_in, const int* in_sizes, int n_in,
                              void* d_out, int out_size, void* d_ws, size_t ws_size,
                              hipStream_t stream)
{
    const float* features = (const float*)d_in[0];  // [32,1024,32,32]
    const float* cam      = (const float*)d_in[1];  // [32,32,32]
    const float* original = (const float*)d_in[2];  // [32,3,512,512]
    const float* w1 = (const float*)d_in[3];        // [512,1024]
    const float* b1 = (const float*)d_in[4];
    const float* w2 = (const float*)d_in[5];        // [256,512]
    const float* b2 = (const float*)d_in[6];
    const float* w3 = (const float*)d_in[7];        // [1,256]
    const float* b3 = (const float*)d_in[8];

    float* out = (float*)d_out;
    unsigned int* h1hi = (unsigned int*)(out + H1HI_OFF);
    unsigned int* h1lo = (unsigned int*)(out + H1LO_OFF);
    float* h2 = out + H2_OFF;
    unsigned short* w1hi = (unsigned short*)(out + W1HI_OFF);
    unsigned short* w1lo = (unsigned short*)(out + W1LO_OFF);
    unsigned short* w2hi = (unsigned short*)(out + W2HI_OFF);
    unsigned short* w2lo = (unsigned short*)(out + W2LO_OFF);
    float* att    = out + ATT_OFF;
    float* coords = out + COORDS_OFF;
    int*   wsyx   = (int*)d_ws;

    dim3 b256(256);
    // P0: pre-split weights
    split_plane<<<dim3(512), b256, 0, stream>>>(w1, w1hi, w1lo, 131072);
    split_plane<<<dim3(128), b256, 0, stream>>>(w2, w2hi, w2lo, 32768);
    // K1: 512 x 32768, K=1024 -> h1 tiled split images
    gemm_k1<<<dim3(1024), b256, 0, stream>>>(w1hi, w1lo, features, b1, h1hi, h1lo);
    // K2: 256 x 32768, K=512, all-DMA from h1 images -> h2 f32
    gemm_k2<<<dim3(512), b256, 0, stream>>>(w2hi, w2lo, h1hi, h1lo, b2, h2);
    // K3
    layer3_att<<<dim3(128), b256, 0, stream>>>(h2, w3, b3, cam, att);
    // K4
    peaks_kernel<<<dim3(32), dim3(64), 0, stream>>>(att, coords, wsyx);
    // K5
    crop_kernel<<<dim3(41472), b256, 0, stream>>>(original, wsyx, out);
}